// Round 1
// baseline (218.401 us; speedup 1.0000x reference)
//
#include <hip/hip_runtime.h>
#include <math.h>

#define BB 256
#define DD 5120
#define NN 16
#define RR 160
#define CT 192   // 160 (t) + 16 (Bm) + 16 (Cm)

// ---------------- zero workspace ----------------
__global__ void kzero(float* __restrict__ p, int n) {
    int i = blockIdx.x * 256 + threadIdx.x;
    if (i < n) p[i] = 0.f;
}

// ---------------- K1: tmp[b,c] = sum_k x[b,k] * Wcat[k,c], split-K atomic ----
// grid: (3 c-tiles, 4 b-tiles, 32 k-splits), block 256
__global__ __launch_bounds__(256) void k1_gemm(const float* __restrict__ x,
                                               const float* __restrict__ Wxdt,
                                               const float* __restrict__ Wbc,
                                               float* __restrict__ tmp) {
    __shared__ float xs[32][68];   // [k][b] transposed, stride 68 (16B-aligned rows for b128)
    __shared__ float ws[32][64];   // [k][c]
    const int tid = threadIdx.x;
    const int tx = tid & 15, ty = tid >> 4;
    const int c0 = blockIdx.x * 64;
    const int b0 = blockIdx.y * 64;
    const int k0 = blockIdx.z * 160;   // 32 splits * 160 = 5120
    float acc[4][4] = {};

    for (int kc = 0; kc < 160; kc += 32) {
        // stage x tile transposed into LDS
        {
            const int i  = tid >> 3;          // 0..31
            const int j4 = (tid & 7) * 4;     // 0,4,...,28
            #pragma unroll
            for (int rep = 0; rep < 2; ++rep) {
                const int row = i + rep * 32; // b-sub 0..63
                const float4 v = *(const float4*)&x[(size_t)(b0 + row) * DD + k0 + kc + j4];
                xs[j4 + 0][row] = v.x;
                xs[j4 + 1][row] = v.y;
                xs[j4 + 2][row] = v.z;
                xs[j4 + 3][row] = v.w;
            }
        }
        // stage W tile (concat of W_x_dt / W_BC columns)
        {
            const int c  = tid & 63;
            const int r0 = tid >> 6;          // 0..3
            const int cg = c0 + c;
            #pragma unroll
            for (int jj = 0; jj < 8; ++jj) {
                const int r  = r0 + jj * 4;
                const int kg = k0 + kc + r;
                float w;
                if (cg < RR) w = Wxdt[(size_t)kg * RR + cg];
                else         w = Wbc[(size_t)kg * 32 + (cg - RR)];
                ws[r][c] = w;
            }
        }
        __syncthreads();
        #pragma unroll
        for (int k = 0; k < 32; ++k) {
            const float4 a4 = *(const float4*)&xs[k][ty * 4];
            const float4 w4 = *(const float4*)&ws[k][tx * 4];
            const float av[4] = {a4.x, a4.y, a4.z, a4.w};
            const float wv[4] = {w4.x, w4.y, w4.z, w4.w};
            #pragma unroll
            for (int u = 0; u < 4; ++u)
                #pragma unroll
                for (int v = 0; v < 4; ++v)
                    acc[u][v] = fmaf(av[u], wv[v], acc[u][v]);
        }
        __syncthreads();
    }

    #pragma unroll
    for (int u = 0; u < 4; ++u) {
        const int b = b0 + ty * 4 + u;
        #pragma unroll
        for (int v = 0; v < 4; ++v) {
            atomicAdd(&tmp[b * CT + c0 + tx * 4 + v], acc[u][v]);
        }
    }
}

// ---------------- K2: dt GEMM (t@W_dt) + fused SSM epilogue ----------------
// grid: (80 d-tiles, 4 b-tiles), block 256
__global__ __launch_bounds__(256) void k2_main(const float* __restrict__ x,
                                               const float* __restrict__ h0,
                                               const float* __restrict__ Wdt,
                                               const float* __restrict__ bdt,
                                               const float* __restrict__ Alog,
                                               const float* __restrict__ tmp,
                                               float* __restrict__ out) {
    __shared__ float ts[32][68];    // [r][b] transposed
    __shared__ float ws[32][64];    // [r][d]
    __shared__ float As[64][17];    // -exp(A_log) for the d-tile, padded
    __shared__ float BCs[64][33];   // per-b: Bm in [0..15], Cm in [16..31]
    __shared__ float bds[64];
    const int tid = threadIdx.x;
    const int tx = tid & 15, ty = tid >> 4;
    const int d0 = blockIdx.x * 64;
    const int b0 = blockIdx.y * 64;

    // stage A = -exp(A_log) for this d-tile (1024 floats)
    {
        const int i  = tid >> 2;         // 0..63
        const int n4 = (tid & 3) * 4;    // 0,4,8,12
        const float4 v = *(const float4*)&Alog[(size_t)(d0 + i) * NN + n4];
        As[i][n4 + 0] = -__expf(v.x);
        As[i][n4 + 1] = -__expf(v.y);
        As[i][n4 + 2] = -__expf(v.z);
        As[i][n4 + 3] = -__expf(v.w);
    }
    // stage Bm/Cm for this b-tile (2048 floats from tmp cols 160..191)
    {
        const int i  = tid >> 3;         // 0..31
        const int c4 = (tid & 7) * 4;    // 0..28
        #pragma unroll
        for (int rep = 0; rep < 2; ++rep) {
            const int row = i + rep * 32;
            const float4 v = *(const float4*)&tmp[(size_t)(b0 + row) * CT + RR + c4];
            BCs[row][c4 + 0] = v.x;
            BCs[row][c4 + 1] = v.y;
            BCs[row][c4 + 2] = v.z;
            BCs[row][c4 + 3] = v.w;
        }
    }
    if (tid < 64) bds[tid] = bdt[d0 + tid];

    float acc[4][4] = {};
    for (int r0 = 0; r0 < RR; r0 += 32) {
        // stage t tile transposed
        {
            const int i  = tid >> 3;
            const int j4 = (tid & 7) * 4;
            #pragma unroll
            for (int rep = 0; rep < 2; ++rep) {
                const int row = i + rep * 32;
                const float4 v = *(const float4*)&tmp[(size_t)(b0 + row) * CT + r0 + j4];
                ts[j4 + 0][row] = v.x;
                ts[j4 + 1][row] = v.y;
                ts[j4 + 2][row] = v.z;
                ts[j4 + 3][row] = v.w;
            }
        }
        // stage W_dt tile
        {
            const int c  = tid & 63;
            const int rr = tid >> 6;
            #pragma unroll
            for (int jj = 0; jj < 8; ++jj) {
                const int r = rr + jj * 4;
                ws[r][c] = Wdt[(size_t)(r0 + r) * DD + d0 + c];
            }
        }
        __syncthreads();
        #pragma unroll
        for (int k = 0; k < 32; ++k) {
            const float4 a4 = *(const float4*)&ts[k][ty * 4];
            const float4 w4 = *(const float4*)&ws[k][tx * 4];
            const float av[4] = {a4.x, a4.y, a4.z, a4.w};
            const float wv[4] = {w4.x, w4.y, w4.z, w4.w};
            #pragma unroll
            for (int u = 0; u < 4; ++u)
                #pragma unroll
                for (int v = 0; v < 4; ++v)
                    acc[u][v] = fmaf(av[u], wv[v], acc[u][v]);
        }
        __syncthreads();
    }

    // fused epilogue: softplus -> delta_A -> h -> y
    #pragma unroll
    for (int u = 0; u < 4; ++u) {
        const int b = b0 + ty * 4 + u;
        const size_t xoff = (size_t)b * DD + d0 + tx * 4;
        const float4 xv = *(const float4*)&x[xoff];
        const float xvs[4] = {xv.x, xv.y, xv.z, xv.w};
        float yv[4];
        #pragma unroll
        for (int v = 0; v < 4; ++v) {
            const int dsub = tx * 4 + v;
            const float z  = acc[u][v] + bds[dsub];
            // stable softplus
            const float dt = fmaxf(z, 0.f) + log1pf(__expf(-fabsf(z)));
            const float xe  = xvs[v];
            const float dtx = dt * xe;
            float acc_y = xe;                       // + x term
            const float* h0p = &h0[(xoff + (size_t)v) * NN];
            #pragma unroll
            for (int n4 = 0; n4 < NN; n4 += 4) {
                const float4 h4 = *(const float4*)&h0p[n4];
                const float hv[4] = {h4.x, h4.y, h4.z, h4.w};
                #pragma unroll
                for (int q = 0; q < 4; ++q) {
                    const int n = n4 + q;
                    const float dA = __expf(As[dsub][n] * dt);
                    const float h  = fmaf(dA, hv[q], dtx * BCs[ty * 4 + u][n]);
                    acc_y = fmaf(h, BCs[ty * 4 + u][16 + n], acc_y);
                }
            }
            yv[v] = acc_y;
        }
        *(float4*)&out[xoff] = make_float4(yv[0], yv[1], yv[2], yv[3]);
    }
}

extern "C" void kernel_launch(void* const* d_in, const int* in_sizes, int n_in,
                              void* d_out, int out_size, void* d_ws, size_t ws_size,
                              hipStream_t stream) {
    const float* x    = (const float*)d_in[0];
    const float* h0   = (const float*)d_in[1];
    const float* Wxdt = (const float*)d_in[2];
    const float* Wdt  = (const float*)d_in[3];
    const float* bdt  = (const float*)d_in[4];
    const float* Wbc  = (const float*)d_in[5];
    const float* Alog = (const float*)d_in[6];
    float* out = (float*)d_out;
    float* tmp = (float*)d_ws;   // 256*192 floats = 196,608 B

    kzero<<<dim3((BB * CT + 255) / 256), 256, 0, stream>>>(tmp, BB * CT);
    k1_gemm<<<dim3(3, 4, 32), 256, 0, stream>>>(x, Wxdt, Wbc, tmp);
    k2_main<<<dim3(DD / 64, BB / 64), 256, 0, stream>>>(x, h0, Wdt, bdt, Alog, tmp, out);
}

// Round 2
// 190.093 us; speedup vs baseline: 1.1489x; 1.1489x over previous
//
#include <hip/hip_runtime.h>
#include <math.h>

#define BB 256
#define DD 5120
#define NN 16
#define RR 160
#define CT 192          // 160 (t) + 16 (Bm) + 16 (Cm)
#define NSPLIT 32
#define TMP_ELEMS (BB * CT)          // 49152
#define NEGA_ELEMS (DD * NN)         // 81920

// ---------------- K1: partials[s][b][c] = x[b, ks:ks+160] @ Wcat[ks:ks+160, c]
// grid: (3 c-tiles, 4 b-tiles, 32 k-splits), block 256. No atomics.
__global__ __launch_bounds__(256) void k1_gemm(const float* __restrict__ x,
                                               const float* __restrict__ Wxdt,
                                               const float* __restrict__ Wbc,
                                               float* __restrict__ part) {
    __shared__ float xs[32][68];   // [k][b] transposed (68: b128-aligned rows)
    __shared__ float ws[32][64];   // [k][c]
    const int tid = threadIdx.x;
    const int tx = tid & 15, ty = tid >> 4;
    const int c0 = blockIdx.x * 64;
    const int b0 = blockIdx.y * 64;
    const int k0 = blockIdx.z * 160;
    float acc[4][4] = {};

    for (int kc = 0; kc < 160; kc += 32) {
        // stage x tile transposed into LDS
        {
            const int i  = tid >> 3;          // 0..31
            const int j4 = (tid & 7) * 4;     // 0..28
            #pragma unroll
            for (int rep = 0; rep < 2; ++rep) {
                const int row = i + rep * 32;
                const float4 v = *(const float4*)&x[(size_t)(b0 + row) * DD + k0 + kc + j4];
                xs[j4 + 0][row] = v.x;
                xs[j4 + 1][row] = v.y;
                xs[j4 + 2][row] = v.z;
                xs[j4 + 3][row] = v.w;
            }
        }
        // stage W tile (vectorized: float4 along c; 160 % 4 == 0 so no straddle)
        {
            const int c4 = (tid & 15) * 4;
            const int r0 = tid >> 4;          // 0..15
            #pragma unroll
            for (int rep = 0; rep < 2; ++rep) {
                const int r  = r0 + rep * 16;
                const int kg = k0 + kc + r;
                const int cg = c0 + c4;
                float4 v;
                if (cg < RR) v = *(const float4*)&Wxdt[(size_t)kg * RR + cg];
                else         v = *(const float4*)&Wbc[(size_t)kg * 32 + (cg - RR)];
                *(float4*)&ws[r][c4] = v;
            }
        }
        __syncthreads();
        #pragma unroll
        for (int k = 0; k < 32; ++k) {
            const float4 a4 = *(const float4*)&xs[k][ty * 4];
            const float4 w4 = *(const float4*)&ws[k][tx * 4];
            const float av[4] = {a4.x, a4.y, a4.z, a4.w};
            const float wv[4] = {w4.x, w4.y, w4.z, w4.w};
            #pragma unroll
            for (int u = 0; u < 4; ++u)
                #pragma unroll
                for (int v = 0; v < 4; ++v)
                    acc[u][v] = fmaf(av[u], wv[v], acc[u][v]);
        }
        __syncthreads();
    }

    float* p = part + (size_t)blockIdx.z * TMP_ELEMS;
    #pragma unroll
    for (int u = 0; u < 4; ++u) {
        const int b = b0 + ty * 4 + u;
        *(float4*)&p[b * CT + c0 + tx * 4] =
            make_float4(acc[u][0], acc[u][1], acc[u][2], acc[u][3]);
    }
}

// ---------------- K_RED: tmp = sum_s partials; negA = -exp(A_log) -----------
// grid: 512 blocks x 256 = 131072 = 49152 + 81920
__global__ __launch_bounds__(256) void k_red(const float* __restrict__ part,
                                             const float* __restrict__ Alog,
                                             float* __restrict__ tmp,
                                             float* __restrict__ negA) {
    const int idx = blockIdx.x * 256 + threadIdx.x;
    if (idx < TMP_ELEMS) {
        float s = 0.f;
        #pragma unroll
        for (int z = 0; z < NSPLIT; ++z) s += part[(size_t)z * TMP_ELEMS + idx];
        tmp[idx] = s;
    } else {
        const int j = idx - TMP_ELEMS;
        negA[j] = -__expf(Alog[j]);
    }
}

// ---------------- K2: dt[b,d] = softplus(t @ W_dt + b_dt) -------------------
// grid: (80 d-tiles of 64, 8 b-tiles of 32), block 256, micro 2b x 4d
__global__ __launch_bounds__(256) void k2_dt(const float* __restrict__ tmp,
                                             const float* __restrict__ Wdt,
                                             const float* __restrict__ bdt,
                                             float* __restrict__ dt) {
    __shared__ float ts[32][34];   // [k][b], stride 34 (b64-aligned, conflict-free)
    __shared__ float ws[32][64];   // [k][d]
    const int tid = threadIdx.x;
    const int tx = tid & 15, ty = tid >> 4;   // tx: d-group, ty: b-pair
    const int d0 = blockIdx.x * 64;
    const int b0 = blockIdx.y * 32;
    float acc[2][4] = {};

    for (int kc = 0; kc < RR; kc += 32) {
        // stage t tile transposed
        {
            const int row = tid >> 3;         // 0..31 (b)
            const int j4  = (tid & 7) * 4;    // 0..28 (k)
            const float4 v = *(const float4*)&tmp[(size_t)(b0 + row) * CT + kc + j4];
            ts[j4 + 0][row] = v.x;
            ts[j4 + 1][row] = v.y;
            ts[j4 + 2][row] = v.z;
            ts[j4 + 3][row] = v.w;
        }
        // stage W_dt tile (float4 along d)
        {
            const int c4 = (tid & 15) * 4;
            const int r0 = tid >> 4;
            #pragma unroll
            for (int rep = 0; rep < 2; ++rep) {
                const int r = r0 + rep * 16;
                *(float4*)&ws[r][c4] = *(const float4*)&Wdt[(size_t)(kc + r) * DD + d0 + c4];
            }
        }
        __syncthreads();
        #pragma unroll
        for (int k = 0; k < 32; ++k) {
            const float a0 = ts[k][ty * 2 + 0];
            const float a1 = ts[k][ty * 2 + 1];
            const float4 w4 = *(const float4*)&ws[k][tx * 4];
            const float wv[4] = {w4.x, w4.y, w4.z, w4.w};
            #pragma unroll
            for (int v = 0; v < 4; ++v) {
                acc[0][v] = fmaf(a0, wv[v], acc[0][v]);
                acc[1][v] = fmaf(a1, wv[v], acc[1][v]);
            }
        }
        __syncthreads();
    }

    const float4 bv = *(const float4*)&bdt[d0 + tx * 4];
    const float bb[4] = {bv.x, bv.y, bv.z, bv.w};
    #pragma unroll
    for (int u = 0; u < 2; ++u) {
        const int b = b0 + ty * 2 + u;
        float o[4];
        #pragma unroll
        for (int v = 0; v < 4; ++v) {
            const float z = acc[u][v] + bb[v];
            o[v] = fmaxf(z, 0.f) + log1pf(__expf(-fabsf(z)));   // stable softplus
        }
        *(float4*)&dt[(size_t)b * DD + d0 + tx * 4] = make_float4(o[0], o[1], o[2], o[3]);
    }
}

// ---------------- K3: streaming epilogue ------------------------------------
// y[b,d] = sum_n (exp(negA[d,n]*dt)*h0[b,d,n] + dt*x*Bm[b,n]) * Cm[b,n] + x
// grid: 1280 blocks x 256; thread handles 4 consecutive d of one b.
__global__ __launch_bounds__(256) void k3_ssm(const float* __restrict__ x,
                                              const float* __restrict__ h0,
                                              const float* __restrict__ dt,
                                              const float* __restrict__ tmp,
                                              const float* __restrict__ negA,
                                              float* __restrict__ out) {
    const int t  = blockIdx.x * 256 + threadIdx.x;       // 0..327679
    const int b  = t / (DD / 4);
    const int dq = t - b * (DD / 4);
    const size_t base = (size_t)b * DD + dq * 4;

    const float4 xv  = *(const float4*)&x[base];
    const float4 dtv = *(const float4*)&dt[base];
    const float xs[4]  = {xv.x, xv.y, xv.z, xv.w};
    const float dts[4] = {dtv.x, dtv.y, dtv.z, dtv.w};

    // Bm/Cm for this b (L1/L2 resident; broadcast across block)
    const float* bc = &tmp[(size_t)b * CT + RR];
    float bm[16], cm[16];
    #pragma unroll
    for (int q4 = 0; q4 < 4; ++q4) {
        const float4 v = *(const float4*)&bc[q4 * 4];
        bm[q4 * 4 + 0] = v.x; bm[q4 * 4 + 1] = v.y; bm[q4 * 4 + 2] = v.z; bm[q4 * 4 + 3] = v.w;
        const float4 w = *(const float4*)&bc[16 + q4 * 4];
        cm[q4 * 4 + 0] = w.x; cm[q4 * 4 + 1] = w.y; cm[q4 * 4 + 2] = w.z; cm[q4 * 4 + 3] = w.w;
    }

    float y[4];
    #pragma unroll
    for (int j = 0; j < 4; ++j) {
        const int d = dq * 4 + j;
        const float dtj = dts[j];
        const float dtx = dtj * xs[j];
        const float* hp = &h0[(base + j) * NN];
        const float* ap = &negA[(size_t)d * NN];
        float acc = xs[j];
        #pragma unroll
        for (int q4 = 0; q4 < 4; ++q4) {
            const float4 a4 = *(const float4*)&ap[q4 * 4];
            const float4 h4 = *(const float4*)&hp[q4 * 4];
            const float av[4] = {a4.x, a4.y, a4.z, a4.w};
            const float hv[4] = {h4.x, h4.y, h4.z, h4.w};
            #pragma unroll
            for (int q = 0; q < 4; ++q) {
                const int n = q4 * 4 + q;
                const float dA = __expf(av[q] * dtj);
                const float h  = fmaf(dA, hv[q], dtx * bm[n]);
                acc = fmaf(h, cm[n], acc);
            }
        }
        y[j] = acc;
    }
    *(float4*)&out[base] = make_float4(y[0], y[1], y[2], y[3]);
}

extern "C" void kernel_launch(void* const* d_in, const int* in_sizes, int n_in,
                              void* d_out, int out_size, void* d_ws, size_t ws_size,
                              hipStream_t stream) {
    const float* x    = (const float*)d_in[0];
    const float* h0   = (const float*)d_in[1];
    const float* Wxdt = (const float*)d_in[2];
    const float* Wdt  = (const float*)d_in[3];
    const float* bdt  = (const float*)d_in[4];
    const float* Wbc  = (const float*)d_in[5];
    const float* Alog = (const float*)d_in[6];
    float* out = (float*)d_out;

    // ws layout (floats): partials[32*49152] | tmp[49152] | negA[81920] | dt[1310720]
    float* part  = (float*)d_ws;
    float* tmp   = part + (size_t)NSPLIT * TMP_ELEMS;
    float* negA  = tmp + TMP_ELEMS;
    float* dtbuf = negA + NEGA_ELEMS;

    k1_gemm<<<dim3(3, 4, NSPLIT), 256, 0, stream>>>(x, Wxdt, Wbc, part);
    k_red<<<dim3((TMP_ELEMS + NEGA_ELEMS) / 256), 256, 0, stream>>>(part, Alog, tmp, negA);
    k2_dt<<<dim3(DD / 64, BB / 32), 256, 0, stream>>>(tmp, Wdt, bdt, dtbuf);
    k3_ssm<<<dim3((BB * DD / 4) / 256), 256, 0, stream>>>(x, h0, dtbuf, tmp, negA, out);
}

// Round 3
// 185.730 us; speedup vs baseline: 1.1759x; 1.0235x over previous
//
#include <hip/hip_runtime.h>
#include <math.h>

#define BB 256
#define DD 5120
#define NN 16
#define RR 160
#define CT 192          // 160 (t) + 16 (Bm) + 16 (Cm)
#define NSPLIT 32
#define TMP_ELEMS (BB * CT)          // 49152
#define NEGA_ELEMS (DD * NN)         // 81920

// ---------------- K1: partials[s][b][c] = x[b, ks:ks+160] @ Wcat[ks:ks+160, c]
// grid: (3 c-tiles, 4 b-tiles, 32 k-splits), block 256. No atomics.
__global__ __launch_bounds__(256) void k1_gemm(const float* __restrict__ x,
                                               const float* __restrict__ Wxdt,
                                               const float* __restrict__ Wbc,
                                               float* __restrict__ part) {
    __shared__ float xs[32][68];   // [k][b] transposed (68: b128-aligned rows)
    __shared__ float ws[32][64];   // [k][c]
    const int tid = threadIdx.x;
    const int tx = tid & 15, ty = tid >> 4;
    const int c0 = blockIdx.x * 64;
    const int b0 = blockIdx.y * 64;
    const int k0 = blockIdx.z * 160;
    float acc[4][4] = {};

    for (int kc = 0; kc < 160; kc += 32) {
        // stage x tile transposed into LDS
        {
            const int i  = tid >> 3;          // 0..31
            const int j4 = (tid & 7) * 4;     // 0..28
            #pragma unroll
            for (int rep = 0; rep < 2; ++rep) {
                const int row = i + rep * 32;
                const float4 v = *(const float4*)&x[(size_t)(b0 + row) * DD + k0 + kc + j4];
                xs[j4 + 0][row] = v.x;
                xs[j4 + 1][row] = v.y;
                xs[j4 + 2][row] = v.z;
                xs[j4 + 3][row] = v.w;
            }
        }
        // stage W tile (float4 along c; both sources are %4 aligned)
        {
            const int c4 = (tid & 15) * 4;
            const int r0 = tid >> 4;          // 0..15
            #pragma unroll
            for (int rep = 0; rep < 2; ++rep) {
                const int r  = r0 + rep * 16;
                const int kg = k0 + kc + r;
                const int cg = c0 + c4;
                float4 v;
                if (cg < RR) v = *(const float4*)&Wxdt[(size_t)kg * RR + cg];
                else         v = *(const float4*)&Wbc[(size_t)kg * 32 + (cg - RR)];
                *(float4*)&ws[r][c4] = v;
            }
        }
        __syncthreads();
        #pragma unroll
        for (int k = 0; k < 32; ++k) {
            const float4 a4 = *(const float4*)&xs[k][ty * 4];
            const float4 w4 = *(const float4*)&ws[k][tx * 4];
            const float av[4] = {a4.x, a4.y, a4.z, a4.w};
            const float wv[4] = {w4.x, w4.y, w4.z, w4.w};
            #pragma unroll
            for (int u = 0; u < 4; ++u)
                #pragma unroll
                for (int v = 0; v < 4; ++v)
                    acc[u][v] = fmaf(av[u], wv[v], acc[u][v]);
        }
        __syncthreads();
    }

    float* p = part + (size_t)blockIdx.z * TMP_ELEMS;
    #pragma unroll
    for (int u = 0; u < 4; ++u) {
        const int b = b0 + ty * 4 + u;
        *(float4*)&p[b * CT + c0 + tx * 4] =
            make_float4(acc[u][0], acc[u][1], acc[u][2], acc[u][3]);
    }
}

// ---------------- K_RED: tmp = sum_s partials; negA = -exp(A_log) -----------
// grid: 512 blocks x 256 = 131072 = 49152 + 81920
__global__ __launch_bounds__(256) void k_red(const float* __restrict__ part,
                                             const float* __restrict__ Alog,
                                             float* __restrict__ tmp,
                                             float* __restrict__ negA) {
    const int idx = blockIdx.x * 256 + threadIdx.x;
    if (idx < TMP_ELEMS) {
        float s = 0.f;
        #pragma unroll
        for (int z = 0; z < NSPLIT; ++z) s += part[(size_t)z * TMP_ELEMS + idx];
        tmp[idx] = s;
    } else {
        const int j = idx - TMP_ELEMS;
        negA[j] = -__expf(Alog[j]);
    }
}

// ---------------- K23: fused dt-GEMM + SSM epilogue -------------------------
// dt = softplus(t @ W_dt + b_dt) stays in registers; then
// y[b,d] = sum_n (exp(negA[d,n]*dt)*h0[b,d,n] + dt*x*Bm[b,n]) * Cm[b,n] + x
// grid: (80 d-tiles of 64, 8 b-tiles of 32), block 256, micro 2b x 4d
__global__ __launch_bounds__(256) void k23_fused(const float* __restrict__ x,
                                                 const float* __restrict__ h0,
                                                 const float* __restrict__ Wdt,
                                                 const float* __restrict__ bdt,
                                                 const float* __restrict__ tmp,
                                                 const float* __restrict__ negA,
                                                 float* __restrict__ out) {
    __shared__ float ts[32][34];   // [k][b]
    __shared__ float ws[32][64];   // [k][d]
    __shared__ float As[64][17];   // negA for the d-tile, padded
    __shared__ float BCs[32][33];  // per-b: Bm [0..15], Cm [16..31]
    const int tid = threadIdx.x;
    const int tx = tid & 15, ty = tid >> 4;   // tx: d-group of 4, ty: b-pair
    const int d0 = blockIdx.x * 64;
    const int b0 = blockIdx.y * 32;

    // stage negA for this d-tile (1024 floats, coalesced)
    {
        const int i  = tid >> 2;         // 0..63
        const int n4 = (tid & 3) * 4;    // 0,4,8,12
        const float4 v = *(const float4*)&negA[(size_t)(d0 + i) * NN + n4];
        As[i][n4 + 0] = v.x; As[i][n4 + 1] = v.y;
        As[i][n4 + 2] = v.z; As[i][n4 + 3] = v.w;
    }
    // stage Bm/Cm for this b-tile (1024 floats)
    {
        const int row = tid >> 3;        // 0..31
        const int c4  = (tid & 7) * 4;   // 0..28
        const float4 v = *(const float4*)&tmp[(size_t)(b0 + row) * CT + RR + c4];
        BCs[row][c4 + 0] = v.x; BCs[row][c4 + 1] = v.y;
        BCs[row][c4 + 2] = v.z; BCs[row][c4 + 3] = v.w;
    }

    float acc[2][4] = {};
    for (int kc = 0; kc < RR; kc += 32) {
        // stage t tile transposed
        {
            const int row = tid >> 3;         // 0..31 (b)
            const int j4  = (tid & 7) * 4;    // 0..28 (k)
            const float4 v = *(const float4*)&tmp[(size_t)(b0 + row) * CT + kc + j4];
            ts[j4 + 0][row] = v.x;
            ts[j4 + 1][row] = v.y;
            ts[j4 + 2][row] = v.z;
            ts[j4 + 3][row] = v.w;
        }
        // stage W_dt tile (float4 along d)
        {
            const int c4 = (tid & 15) * 4;
            const int r0 = tid >> 4;
            #pragma unroll
            for (int rep = 0; rep < 2; ++rep) {
                const int r = r0 + rep * 16;
                *(float4*)&ws[r][c4] = *(const float4*)&Wdt[(size_t)(kc + r) * DD + d0 + c4];
            }
        }
        __syncthreads();
        #pragma unroll
        for (int k = 0; k < 32; ++k) {
            const float a0 = ts[k][ty * 2 + 0];
            const float a1 = ts[k][ty * 2 + 1];
            const float4 w4 = *(const float4*)&ws[k][tx * 4];
            const float wv[4] = {w4.x, w4.y, w4.z, w4.w};
            #pragma unroll
            for (int v = 0; v < 4; ++v) {
                acc[0][v] = fmaf(a0, wv[v], acc[0][v]);
                acc[1][v] = fmaf(a1, wv[v], acc[1][v]);
            }
        }
        __syncthreads();
    }

    const float4 bv = *(const float4*)&bdt[d0 + tx * 4];
    const float bb[4] = {bv.x, bv.y, bv.z, bv.w};

    #pragma unroll
    for (int u = 0; u < 2; ++u) {
        const int b = b0 + ty * 2 + u;
        const size_t base = (size_t)b * DD + d0 + tx * 4;
        const float4 xv = *(const float4*)&x[base];
        const float xs4[4] = {xv.x, xv.y, xv.z, xv.w};
        const float* bm = &BCs[ty * 2 + u][0];
        const float* cm = &BCs[ty * 2 + u][16];
        float y[4];
        #pragma unroll
        for (int v = 0; v < 4; ++v) {
            const int dsub = tx * 4 + v;
            const float z  = acc[u][v] + bb[v];
            const float dt = fmaxf(z, 0.f) + log1pf(__expf(-fabsf(z)));  // softplus
            const float xe = xs4[v];
            const float dtx = dt * xe;
            const float* hp = &h0[(base + (size_t)v) * NN];
            float acc_y = xe;
            #pragma unroll
            for (int n4 = 0; n4 < NN; n4 += 4) {
                const float4 a4 = *(const float4*)&As[dsub][n4];
                const float4 h4 = *(const float4*)&hp[n4];
                const float av[4] = {a4.x, a4.y, a4.z, a4.w};
                const float hv[4] = {h4.x, h4.y, h4.z, h4.w};
                #pragma unroll
                for (int q = 0; q < 4; ++q) {
                    const int n = n4 + q;
                    const float dA = __expf(av[q] * dt);
                    const float h  = fmaf(dA, hv[q], dtx * bm[n]);
                    acc_y = fmaf(h, cm[n], acc_y);
                }
            }
            y[v] = acc_y;
        }
        *(float4*)&out[base] = make_float4(y[0], y[1], y[2], y[3]);
    }
}

extern "C" void kernel_launch(void* const* d_in, const int* in_sizes, int n_in,
                              void* d_out, int out_size, void* d_ws, size_t ws_size,
                              hipStream_t stream) {
    const float* x    = (const float*)d_in[0];
    const float* h0   = (const float*)d_in[1];
    const float* Wxdt = (const float*)d_in[2];
    const float* Wdt  = (const float*)d_in[3];
    const float* bdt  = (const float*)d_in[4];
    const float* Wbc  = (const float*)d_in[5];
    const float* Alog = (const float*)d_in[6];
    float* out = (float*)d_out;

    // ws layout (floats): partials[32*49152] | tmp[49152] | negA[81920]
    float* part = (float*)d_ws;
    float* tmp  = part + (size_t)NSPLIT * TMP_ELEMS;
    float* negA = tmp + TMP_ELEMS;

    k1_gemm<<<dim3(3, 4, NSPLIT), 256, 0, stream>>>(x, Wxdt, Wbc, part);
    k_red<<<dim3((TMP_ELEMS + NEGA_ELEMS) / 256), 256, 0, stream>>>(part, Alog, tmp, negA);
    k23_fused<<<dim3(DD / 64, BB / 32), 256, 0, stream>>>(x, h0, Wdt, bdt, tmp, negA, out);
}